// Round 3
// baseline (262.130 us; speedup 1.0000x reference)
//
#include <hip/hip_runtime.h>

#define ALPHA 0.2f

typedef __attribute__((ext_vector_type(8))) short short8;
typedef __attribute__((ext_vector_type(4))) float f32x4;

// ---------- helpers ----------
__device__ __forceinline__ unsigned short f2b(float f) {
  // round-to-nearest-even f32 -> bf16 bits
  unsigned int u; __builtin_memcpy(&u, &f, 4);
  unsigned int r = (u + 0x7FFFu + ((u >> 16) & 1u)) >> 16;
  return (unsigned short)r;
}
__device__ __forceinline__ float b2f(unsigned short v) {
  unsigned int u = ((unsigned int)v) << 16; float f; __builtin_memcpy(&f, &u, 4); return f;
}
__device__ __forceinline__ void gl_lds16(const unsigned short* g, unsigned short* l) {
  // async global->LDS, 16B/lane; LDS dst = wave-uniform base + lane*16
  __builtin_amdgcn_global_load_lds((__attribute__((address_space(1))) void*)g,
                                   (__attribute__((address_space(3))) void*)l, 16, 0, 0);
}
__device__ __forceinline__ uint4 pack8(float4 v0, float4 v1) {
  alignas(16) unsigned short o[8];
  o[0] = f2b(v0.x); o[1] = f2b(v0.y); o[2] = f2b(v0.z); o[3] = f2b(v0.w);
  o[4] = f2b(v1.x); o[5] = f2b(v1.y); o[6] = f2b(v1.z); o[7] = f2b(v1.w);
  return *(const uint4*)o;
}

// lane-contiguous fp32->bf16: one coalesced float4 load -> coalesced 8B store
__device__ __forceinline__ void cvt_f4(const float* __restrict__ in,
                                       unsigned short* __restrict__ out,
                                       unsigned int f4idx) {
  float4 v = ((const float4*)in)[f4idx];
  alignas(8) unsigned short o[4];
  o[0] = f2b(v.x); o[1] = f2b(v.y); o[2] = f2b(v.z); o[3] = f2b(v.w);
  ((uint2*)out)[f4idx] = *(const uint2*)o;
}

// ---------- prep1 (tiny): cvt fcw->bf16 + transpose W ----------
__global__ __launch_bounds__(256) void prep1(const float* __restrict__ fcw,
                                             unsigned short* __restrict__ fcwb,
                                             const float* __restrict__ W,
                                             unsigned short* __restrict__ Wt) {
  __shared__ alignas(16) unsigned short tile[64][72];
  unsigned int bx = blockIdx.x;
  unsigned int tid = threadIdx.x;
  if (bx < 256u) {
    unsigned int base = bx * 512u;
    cvt_f4(fcw, fcwb, base + tid);
    cvt_f4(fcw, fcwb, base + 256u + tid);
  } else {
    // W transpose: tile (k0..k0+64) x (n0..n0+64)
    unsigned int idx = bx - 256u;                 // 128 blocks: 16 k-tiles x 8 n-tiles
    unsigned int k0 = (idx >> 3) * 64, n0 = (idx & 7) * 64;
    #pragma unroll
    for (int p = 0; p < 4; p++) {
      int r = p * 16 + (tid >> 4);
      int c = (tid & 15) * 4;
      float4 v = *(const float4*)(W + (size_t)(k0 + r) * 512 + n0 + c);
      tile[r][c] = f2b(v.x); tile[r][c + 1] = f2b(v.y);
      tile[r][c + 2] = f2b(v.z); tile[r][c + 3] = f2b(v.w);
    }
    __syncthreads();
    int f = tid >> 2;
    int ic = (tid & 3) * 16;
    alignas(16) unsigned short buf[16];
    #pragma unroll
    for (int k = 0; k < 16; k++) buf[k] = tile[ic + k][f];
    uint4* dst = (uint4*)(Wt + (size_t)(n0 + f) * 1024 + k0 + ic);
    dst[0] = ((const uint4*)buf)[0];
    dst[1] = ((const uint4*)buf)[1];
  }
}

// ---------- prep2: f1f2 + transpose_h (both depend only on GEMM1) ----------
__global__ __launch_bounds__(256) void prep2(const unsigned short* __restrict__ hp,
                                             const float* __restrict__ a,
                                             float* __restrict__ f1, float* __restrict__ f2,
                                             unsigned short* __restrict__ ht) {
  __shared__ alignas(16) unsigned short tile[64][72];
  int bx = blockIdx.x;
  int tid = threadIdx.x;
  if (bx < 4096) {
    // f1[m]=h[m]·a1, f2[m]=h[m]·a2 ; one wave per row
    int row = bx * 4 + (tid >> 6);
    int lane = tid & 63;
    const unsigned short* hrow = hp + (size_t)row * 1024 + 512;
    uint4 raw = *(const uint4*)(hrow + lane * 8);
    alignas(16) unsigned short hv[8]; __builtin_memcpy(hv, &raw, 16);
    float s1 = 0.f, s2 = 0.f;
    #pragma unroll
    for (int j = 0; j < 8; j++) {
      float hf = b2f(hv[j]);
      s1 += hf * a[lane * 8 + j];
      s2 += hf * a[512 + lane * 8 + j];
    }
    #pragma unroll
    for (int o = 32; o > 0; o >>= 1) { s1 += __shfl_down(s1, o); s2 += __shfl_down(s2, o); }
    if (lane == 0) { f1[row] = s1; f2[row] = s2; }
  } else {
    // hp h-half -> ht[b][f][i] (B^T layout for attention GEMM), 64x64 LDS tile transpose
    int idx = bx - 4096;                 // 2048 blocks: (16 b) x (8 f0) x (16 i0)
    int b = idx >> 7;
    int f0 = ((idx >> 4) & 7) * 64;
    int i0 = (idx & 15) * 64;
    #pragma unroll
    for (int p = 0; p < 2; p++) {
      int r = p * 32 + (tid >> 3);
      int c = (tid & 7) * 8;
      uint4 v = *(const uint4*)(hp + (size_t)(b * 1024 + i0 + r) * 1024 + 512 + f0 + c);
      *(uint4*)(&tile[r][c]) = v;
    }
    __syncthreads();
    int f = tid >> 2;
    int ic = (tid & 3) * 16;
    alignas(16) unsigned short buf[16];
    #pragma unroll
    for (int k = 0; k < 16; k++) buf[k] = tile[ic + k][f];
    uint4* dst = (uint4*)(ht + (size_t)(b * 512 + f0 + f) * 1024 + i0 + ic);
    dst[0] = ((const uint4*)buf)[0];
    dst[1] = ((const uint4*)buf)[1];
  }
}

// ---------- rowsum + P in one pass, reading adj DIRECTLY ----------
__global__ __launch_bounds__(256) void rowsum_P(const int* __restrict__ adj,
                                                const float* __restrict__ f1,
                                                const float* __restrict__ f2,
                                                float* __restrict__ invl,
                                                unsigned short* __restrict__ P) {
  int row = blockIdx.x * 4 + (threadIdx.x >> 6);
  int lane = threadIdx.x & 63;
  int b = row >> 10;
  float f1v = f1[row];
  const int4* ap = (const int4*)(adj + (size_t)row * 1024) + lane * 4;
  int4 a0 = ap[0];
  int4 a1 = ap[1];
  int4 a2 = ap[2];
  int4 a3 = ap[3];
  int av[16] = {a0.x, a0.y, a0.z, a0.w, a1.x, a1.y, a1.z, a1.w,
                a2.x, a2.y, a2.z, a2.w, a3.x, a3.y, a3.z, a3.w};
  const float* f2p = f2 + (b << 10) + lane * 16;
  float4 v0 = ((const float4*)f2p)[0];
  float4 v1 = ((const float4*)f2p)[1];
  float4 v2 = ((const float4*)f2p)[2];
  float4 v3 = ((const float4*)f2p)[3];
  float fv[16] = {v0.x, v0.y, v0.z, v0.w, v1.x, v1.y, v1.z, v1.w,
                  v2.x, v2.y, v2.z, v2.w, v3.x, v3.y, v3.z, v3.w};
  float s = 0.f;
  alignas(16) unsigned short o[16];
  #pragma unroll
  for (int j = 0; j < 16; j++) {
    float p = 0.f;
    if (av[j] > 0) {
      float z = f1v + fv[j];
      z = z > 0.f ? z : ALPHA * z;
      p = __expf(z);
      s += p;
    }
    o[j] = f2b(p);
  }
  uint4* dst = (uint4*)(P + (size_t)row * 1024 + lane * 16);
  dst[0] = ((const uint4*)o)[0];
  dst[1] = ((const uint4*)o)[1];
  #pragma unroll
  for (int off = 32; off > 0; off >>= 1) s += __shfl_down(s, off);
  if (lane == 0) invl[row] = 1.0f / s;
}

// ---------- bf16 GEMM: C(MxN) = A(MxK) @ Bt(NxK)^T ----------
// 128x128 tile, BK=64, 4 waves each 64x64 (4x4 of 16x16x32 MFMA).
// Double-buffered 2-phase + XCD-chunked bijective block swizzle (T1):
// HW round-robins dispatch index over 8 XCDs; remap so each XCD owns a
// contiguous y-fastest chunk -> A-panel sharers co-resident in that XCD's
// L2, B-panels cycle L2-resident. Per-K-step chunk working set << 4MB L2.
// CVTA=1: A is fp32 (x directly); reg-staged cvt (issue-early/write-late).
// EPI 1: bf16 out at [m][ocol+n]   (h -> hp right half)
// EPI 2: fp32 out, +bias, ELU      (final output)
// EPI 3: bf16 out, * scale[row]    (agg -> hp left half, scale = 1/l)
template <int EPI, int CVTA>
__global__ __launch_bounds__(256) void gemm_bt(
    const void* __restrict__ A_, size_t aBS,
    const unsigned short* __restrict__ Bt, size_t bBS,
    int K,
    void* __restrict__ outp, size_t oBS, int ldo, int ocol,
    const float* __restrict__ scale,
    const float* __restrict__ bias) {
  __shared__ alignas(16) unsigned short As[2 * 128 * 64];
  __shared__ alignas(16) unsigned short Bs[2 * 128 * 64];
  const int tid = threadIdx.x;
  const int lane = tid & 63;
  const int w = tid >> 6;

  // ---- XCD-chunked bijective remap (T1), y-fastest decode ----
  const int gx = gridDim.x, gy = gridDim.y, gz = gridDim.z;
  const int nlin = gx * gy * gz;
  int bx, by, bz;
  {
    int lin = blockIdx.x + gx * (blockIdx.y + gy * blockIdx.z);  // dispatch order
    if ((nlin & 7) == 0) {
      int lin2 = (lin & 7) * (nlin >> 3) + (lin >> 3);           // chunk per XCD
      by = lin2 % gy;
      int t = lin2 / gy;
      bx = t % gx;
      bz = t / gx;
    } else {
      bx = blockIdx.x; by = blockIdx.y; bz = blockIdx.z;
    }
  }
  const int m0 = bx * 128;
  const int n0 = by * 128;
  const int zb = bz;
  const unsigned short* Btb = Bt + (size_t)zb * bBS;

  f32x4 acc[4][4];
  #pragma unroll
  for (int i = 0; i < 4; i++)
    #pragma unroll
    for (int j = 0; j < 4; j++)
      #pragma unroll
      for (int r = 0; r < 4; r++) acc[i][j][r] = 0.f;

  // staging addresses: lane L covers 16B(bf16)/8floats of row (w*32 + t*8 + L/8)
  const int lr = lane >> 3;                 // row within 8-row group
  const int lc = (lane & 7) ^ (lr & 7);     // swizzled global col-block
  const unsigned short* ag = nullptr;
  const float* agf = nullptr;
  if (CVTA)
    agf = (const float*)A_ + (size_t)zb * aBS + (size_t)(m0 + w * 32 + lr) * K + lc * 8;
  else
    ag = (const unsigned short*)A_ + (size_t)zb * aBS + (size_t)(m0 + w * 32 + lr) * K + lc * 8;
  const unsigned short* bg = Btb + (size_t)(n0 + w * 32 + lr) * K + lc * 8;
  const int sbase = w * 32 * 64;            // per-wave LDS staging base (shorts)
  const int lofs = lane * 8;                // per-lane LDS dst (shorts) for reg-staged A

  const int wm = (w & 1) * 64;
  const int wn = (w >> 1) * 64;
  const int row16 = lane & 15;
  const int quad = lane >> 4;
  const int sw = row16 & 7;                 // fragment-read swizzle

  // prologue: stage tile k0=0 into buffer 0
  if (CVTA) {
    float4 av[4][2];
    #pragma unroll
    for (int t = 0; t < 4; t++) {
      av[t][0] = *(const float4*)(agf + (size_t)(t * 8) * K);
      av[t][1] = *(const float4*)(agf + (size_t)(t * 8) * K + 4);
    }
    #pragma unroll
    for (int t = 0; t < 4; t++)
      gl_lds16(bg + (size_t)(t * 8) * K, Bs + sbase + t * 512);
    #pragma unroll
    for (int t = 0; t < 4; t++)
      *(uint4*)(As + sbase + t * 512 + lofs) = pack8(av[t][0], av[t][1]);
  } else {
    #pragma unroll
    for (int t = 0; t < 4; t++) {
      gl_lds16(ag + (size_t)(t * 8) * K, As + sbase + t * 512);
      gl_lds16(bg + (size_t)(t * 8) * K, Bs + sbase + t * 512);
    }
  }
  __syncthreads();                          // drains vmcnt(0)+lgkmcnt(0) + barrier

  int bufo = 0;                             // current buffer offset (shorts)
  for (int k0 = 0; k0 < K; k0 += 64) {
    const int nbufo = bufo ^ 8192;
    const bool pf = (k0 + 64 < K);
    float4 av[4][2];
    if (pf) {                               // issue next-tile loads EARLY
      if (CVTA) {
        #pragma unroll
        for (int t = 0; t < 4; t++) {
          av[t][0] = *(const float4*)(agf + (k0 + 64) + (size_t)(t * 8) * K);
          av[t][1] = *(const float4*)(agf + (k0 + 64) + (size_t)(t * 8) * K + 4);
        }
      } else {
        #pragma unroll
        for (int t = 0; t < 4; t++)
          gl_lds16(ag + (k0 + 64) + (size_t)(t * 8) * K, As + nbufo + sbase + t * 512);
      }
      #pragma unroll
      for (int t = 0; t < 4; t++)
        gl_lds16(bg + (k0 + 64) + (size_t)(t * 8) * K, Bs + nbufo + sbase + t * 512);
    }
    short8 af[2][4], bf[2][4];
    #pragma unroll
    for (int s = 0; s < 2; s++) {
      #pragma unroll
      for (int i = 0; i < 4; i++) {
        af[s][i] = *(const short8*)(As + bufo + (wm + i * 16 + row16) * 64 + ((s * 4 + quad) ^ sw) * 8);
        bf[s][i] = *(const short8*)(Bs + bufo + (wn + i * 16 + row16) * 64 + ((s * 4 + quad) ^ sw) * 8);
      }
    }
    #pragma unroll
    for (int s = 0; s < 2; s++)
      #pragma unroll
      for (int am = 0; am < 4; am++)
        #pragma unroll
        for (int bn = 0; bn < 4; bn++)
          acc[am][bn] = __builtin_amdgcn_mfma_f32_16x16x32_bf16(af[s][am], bf[s][bn], acc[am][bn], 0, 0, 0);
    if (pf && CVTA) {                       // write-late: cvt+ds_write after MFMA
      #pragma unroll
      for (int t = 0; t < 4; t++)
        *(uint4*)(As + nbufo + sbase + t * 512 + lofs) = pack8(av[t][0], av[t][1]);
    }
    __syncthreads();                        // prefetch landed; reads of bufo done
    bufo = nbufo;
  }

  // C/D layout: col = lane&15, row = (lane>>4)*4 + reg  [m89/m91-verified]
  const int col = lane & 15;
  const int r0 = quad * 4;
  #pragma unroll
  for (int am = 0; am < 4; am++) {
    #pragma unroll
    for (int bn = 0; bn < 4; bn++) {
      #pragma unroll
      for (int r = 0; r < 4; r++) {
        int m = m0 + wm + am * 16 + r0 + r;
        int n = n0 + wn + bn * 16 + col;
        float v = acc[am][bn][r];
        if (EPI == 3) v *= scale[zb * 1024 + m];
        if (EPI == 2) {
          v += bias[n];
          v = v > 0.f ? v : expm1f(v);   // ELU, alpha=1
          ((float*)outp)[(size_t)m * ldo + n] = v;
        } else {
          ((unsigned short*)outp)[(size_t)zb * oBS + (size_t)m * ldo + ocol + n] = f2b(v);
        }
      }
    }
  }
}

// ---------- launch ----------
extern "C" void kernel_launch(void* const* d_in, const int* in_sizes, int n_in,
                              void* d_out, int out_size, void* d_ws, size_t ws_size,
                              hipStream_t stream) {
  const float* x   = (const float*)d_in[0];  // (16,1024,1024)
  const int*   adj = (const int*)d_in[1];    // (16,1024,1024)
  const float* W   = (const float*)d_in[2];  // (1024,512)
  const float* a   = (const float*)d_in[3];  // (1024,1)
  const float* fcw = (const float*)d_in[4];  // (512,1024)  == Bt layout for GEMM3
  const float* fcb = (const float*)d_in[5];  // (512,)
  float* out = (float*)d_out;                // (16,1024,512) fp32
  char* ws = (char*)d_ws;

  // ws layout (~84.2 MiB)
  unsigned short* P    = (unsigned short*)(ws);               // 32MB P~ bf16
  unsigned short* hp   = (unsigned short*)(ws + 33554432);    // 32MB [agg | h] bf16 rows
  unsigned short* ht   = (unsigned short*)(ws + 67108864);    // 16MB h^T per batch
  unsigned short* Wt   = (unsigned short*)(ws + 83886080);    // 1MB
  unsigned short* fcwb = (unsigned short*)(ws + 84934656);    // 1MB
  float* f1            = (float*)(ws + 85983232);             // 64KB
  float* f2            = (float*)(ws + 86048768);             // 64KB
  float* invl          = (float*)(ws + 86114304);             // 64KB

  // 1: tiny prep (fcw cvt + W transpose)
  prep1<<<384, 256, 0, stream>>>(fcw, fcwb, W, Wt);

  // 2: GEMM1  h = x @ W  -> hp[:,512:1024]   (A = x fp32, cvt fused in staging)
  gemm_bt<1, 1><<<dim3(128, 4, 1), 256, 0, stream>>>(x, 0, Wt, 0, 1024,
                                                     hp, 0, 1024, 512, nullptr, nullptr);
  // 3: f1/f2 + h^T
  prep2<<<6144, 256, 0, stream>>>(hp, a, f1, f2, ht);
  // 4: P~ (unnormalized, bf16) + 1/rowsum   (reads adj directly)
  rowsum_P<<<4096, 256, 0, stream>>>(adj, f1, f2, invl, P);

  // 5: GEMM2 (per batch): agg = (P~ @ h) * invl  -> hp[:,0:512]
  gemm_bt<3, 0><<<dim3(8, 4, 16), 256, 0, stream>>>(P, 1024 * 1024, ht, 512 * 1024, 1024,
                                                    hp, 1024 * 1024, 1024, 0, invl, nullptr);
  // 6: GEMM3: out = elu([agg|h] @ fc_w^T + b)
  gemm_bt<2, 0><<<dim3(128, 4, 1), 256, 0, stream>>>(hp, 0, fcwb, 0, 1024,
                                                     out, 0, 512, 0, nullptr, fcb);
}

// Round 4
// 251.653 us; speedup vs baseline: 1.0416x; 1.0416x over previous
//
#include <hip/hip_runtime.h>

#define ALPHA 0.2f

typedef __attribute__((ext_vector_type(8))) short short8;
typedef __attribute__((ext_vector_type(4))) float f32x4;

// ---------- helpers ----------
__device__ __forceinline__ unsigned short f2b(float f) {
  // round-to-nearest-even f32 -> bf16 bits
  unsigned int u; __builtin_memcpy(&u, &f, 4);
  unsigned int r = (u + 0x7FFFu + ((u >> 16) & 1u)) >> 16;
  return (unsigned short)r;
}
__device__ __forceinline__ float b2f(unsigned short v) {
  unsigned int u = ((unsigned int)v) << 16; float f; __builtin_memcpy(&f, &u, 4); return f;
}
__device__ __forceinline__ void gl_lds16(const unsigned short* g, unsigned short* l) {
  // async global->LDS, 16B/lane; LDS dst = wave-uniform base + lane*16
  __builtin_amdgcn_global_load_lds((__attribute__((address_space(1))) void*)g,
                                   (__attribute__((address_space(3))) void*)l, 16, 0, 0);
}
__device__ __forceinline__ uint4 pack8(float4 v0, float4 v1) {
  alignas(16) unsigned short o[8];
  o[0] = f2b(v0.x); o[1] = f2b(v0.y); o[2] = f2b(v0.z); o[3] = f2b(v0.w);
  o[4] = f2b(v1.x); o[5] = f2b(v1.y); o[6] = f2b(v1.z); o[7] = f2b(v1.w);
  return *(const uint4*)o;
}

// lane-contiguous fp32->bf16: one coalesced float4 load -> coalesced 8B store
__device__ __forceinline__ void cvt_f4(const float* __restrict__ in,
                                       unsigned short* __restrict__ out,
                                       unsigned int f4idx) {
  float4 v = ((const float4*)in)[f4idx];
  alignas(8) unsigned short o[4];
  o[0] = f2b(v.x); o[1] = f2b(v.y); o[2] = f2b(v.z); o[3] = f2b(v.w);
  ((uint2*)out)[f4idx] = *(const uint2*)o;
}

// ---------- prep1 (tiny): cvt fcw->bf16 + transpose W ----------
__global__ __launch_bounds__(256) void prep1(const float* __restrict__ fcw,
                                             unsigned short* __restrict__ fcwb,
                                             const float* __restrict__ W,
                                             unsigned short* __restrict__ Wt) {
  __shared__ alignas(16) unsigned short tile[64][72];
  unsigned int bx = blockIdx.x;
  unsigned int tid = threadIdx.x;
  if (bx < 256u) {
    unsigned int base = bx * 512u;
    cvt_f4(fcw, fcwb, base + tid);
    cvt_f4(fcw, fcwb, base + 256u + tid);
  } else {
    // W transpose: tile (k0..k0+64) x (n0..n0+64)
    unsigned int idx = bx - 256u;                 // 128 blocks: 16 k-tiles x 8 n-tiles
    unsigned int k0 = (idx >> 3) * 64, n0 = (idx & 7) * 64;
    #pragma unroll
    for (int p = 0; p < 4; p++) {
      int r = p * 16 + (tid >> 4);
      int c = (tid & 15) * 4;
      float4 v = *(const float4*)(W + (size_t)(k0 + r) * 512 + n0 + c);
      tile[r][c] = f2b(v.x); tile[r][c + 1] = f2b(v.y);
      tile[r][c + 2] = f2b(v.z); tile[r][c + 3] = f2b(v.w);
    }
    __syncthreads();
    int f = tid >> 2;
    int ic = (tid & 3) * 16;
    alignas(16) unsigned short buf[16];
    #pragma unroll
    for (int k = 0; k < 16; k++) buf[k] = tile[ic + k][f];
    uint4* dst = (uint4*)(Wt + (size_t)(n0 + f) * 1024 + k0 + ic);
    dst[0] = ((const uint4*)buf)[0];
    dst[1] = ((const uint4*)buf)[1];
  }
}

// ---------- prep2: f1f2 + transpose_h (both depend only on GEMM1) ----------
__global__ __launch_bounds__(256) void prep2(const unsigned short* __restrict__ hp,
                                             const float* __restrict__ a,
                                             float* __restrict__ f1, float* __restrict__ f2,
                                             unsigned short* __restrict__ ht) {
  __shared__ alignas(16) unsigned short tile[64][72];
  int bx = blockIdx.x;
  int tid = threadIdx.x;
  if (bx < 4096) {
    // f1[m]=h[m]·a1, f2[m]=h[m]·a2 ; one wave per row
    int row = bx * 4 + (tid >> 6);
    int lane = tid & 63;
    const unsigned short* hrow = hp + (size_t)row * 1024 + 512;
    uint4 raw = *(const uint4*)(hrow + lane * 8);
    alignas(16) unsigned short hv[8]; __builtin_memcpy(hv, &raw, 16);
    float s1 = 0.f, s2 = 0.f;
    #pragma unroll
    for (int j = 0; j < 8; j++) {
      float hf = b2f(hv[j]);
      s1 += hf * a[lane * 8 + j];
      s2 += hf * a[512 + lane * 8 + j];
    }
    #pragma unroll
    for (int o = 32; o > 0; o >>= 1) { s1 += __shfl_down(s1, o); s2 += __shfl_down(s2, o); }
    if (lane == 0) { f1[row] = s1; f2[row] = s2; }
  } else {
    // hp h-half -> ht[b][f][i] (B^T layout for attention GEMM), 64x64 LDS tile transpose
    int idx = bx - 4096;                 // 2048 blocks: (16 b) x (8 f0) x (16 i0)
    int b = idx >> 7;
    int f0 = ((idx >> 4) & 7) * 64;
    int i0 = (idx & 15) * 64;
    #pragma unroll
    for (int p = 0; p < 2; p++) {
      int r = p * 32 + (tid >> 3);
      int c = (tid & 7) * 8;
      uint4 v = *(const uint4*)(hp + (size_t)(b * 1024 + i0 + r) * 1024 + 512 + f0 + c);
      *(uint4*)(&tile[r][c]) = v;
    }
    __syncthreads();
    int f = tid >> 2;
    int ic = (tid & 3) * 16;
    alignas(16) unsigned short buf[16];
    #pragma unroll
    for (int k = 0; k < 16; k++) buf[k] = tile[ic + k][f];
    uint4* dst = (uint4*)(ht + (size_t)(b * 512 + f0 + f) * 1024 + i0 + ic);
    dst[0] = ((const uint4*)buf)[0];
    dst[1] = ((const uint4*)buf)[1];
  }
}

// ---------- rowsum + P in one pass, reading adj DIRECTLY ----------
__global__ __launch_bounds__(256) void rowsum_P(const int* __restrict__ adj,
                                                const float* __restrict__ f1,
                                                const float* __restrict__ f2,
                                                float* __restrict__ invl,
                                                unsigned short* __restrict__ P) {
  int row = blockIdx.x * 4 + (threadIdx.x >> 6);
  int lane = threadIdx.x & 63;
  int b = row >> 10;
  float f1v = f1[row];
  const int4* ap = (const int4*)(adj + (size_t)row * 1024) + lane * 4;
  int4 a0 = ap[0];
  int4 a1 = ap[1];
  int4 a2 = ap[2];
  int4 a3 = ap[3];
  int av[16] = {a0.x, a0.y, a0.z, a0.w, a1.x, a1.y, a1.z, a1.w,
                a2.x, a2.y, a2.z, a2.w, a3.x, a3.y, a3.z, a3.w};
  const float* f2p = f2 + (b << 10) + lane * 16;
  float4 v0 = ((const float4*)f2p)[0];
  float4 v1 = ((const float4*)f2p)[1];
  float4 v2 = ((const float4*)f2p)[2];
  float4 v3 = ((const float4*)f2p)[3];
  float fv[16] = {v0.x, v0.y, v0.z, v0.w, v1.x, v1.y, v1.z, v1.w,
                  v2.x, v2.y, v2.z, v2.w, v3.x, v3.y, v3.z, v3.w};
  float s = 0.f;
  alignas(16) unsigned short o[16];
  #pragma unroll
  for (int j = 0; j < 16; j++) {
    float p = 0.f;
    if (av[j] > 0) {
      float z = f1v + fv[j];
      z = z > 0.f ? z : ALPHA * z;
      p = __expf(z);
      s += p;
    }
    o[j] = f2b(p);
  }
  uint4* dst = (uint4*)(P + (size_t)row * 1024 + lane * 16);
  dst[0] = ((const uint4*)o)[0];
  dst[1] = ((const uint4*)o)[1];
  #pragma unroll
  for (int off = 32; off > 0; off >>= 1) s += __shfl_down(s, off);
  if (lane == 0) invl[row] = 1.0f / s;
}

// ---------- bf16 GEMM: C(MxN) = A(MxK) @ Bt(NxK)^T ----------
// 128x128 tile, BK=64, 512 THREADS = 8 waves, each computing 64x32 (2m x 4n
// wave grid; acc[4][2]). Grid is only 512 blocks (= 2 blocks/CU max), so
// occupancy is grid-limited: 8 waves/block doubles resident waves/CU 8->16
// (4/SIMD) without touching grid, LDS, or locality. Double-buffered 2-phase:
// issue next K-tile loads before current ds_read+MFMA, one __syncthreads per
// K-step. CVTA=1: A fp32 (x directly), reg-staged cvt issue-early/write-late.
// XOR-swizzled LDS: logical (row, colblk cb) at physical cb^(row&7).
// EPI 1: bf16 out at [m][ocol+n]   (h -> hp right half)
// EPI 2: fp32 out, +bias, ELU      (final output)
// EPI 3: bf16 out, * scale[row]    (agg -> hp left half, scale = 1/l)
template <int EPI, int CVTA>
__global__ __launch_bounds__(512, 4) void gemm_bt(
    const void* __restrict__ A_, size_t aBS,
    const unsigned short* __restrict__ Bt, size_t bBS,
    int K,
    void* __restrict__ outp, size_t oBS, int ldo, int ocol,
    const float* __restrict__ scale,
    const float* __restrict__ bias) {
  __shared__ alignas(16) unsigned short As[2 * 128 * 64];
  __shared__ alignas(16) unsigned short Bs[2 * 128 * 64];
  const int tid = threadIdx.x;
  const int lane = tid & 63;
  const int w = tid >> 6;                   // 0..7
  const int m0 = blockIdx.x * 128;
  const int n0 = blockIdx.y * 128;
  const int zb = blockIdx.z;
  const unsigned short* Btb = Bt + (size_t)zb * bBS;

  f32x4 acc[4][2];
  #pragma unroll
  for (int i = 0; i < 4; i++)
    #pragma unroll
    for (int j = 0; j < 2; j++)
      #pragma unroll
      for (int r = 0; r < 4; r++) acc[i][j][r] = 0.f;

  // staging: pass t in {0,1}; wave w covers rows t*64 + w*8 + (0..7);
  // lane L covers 16B of row t*64 + w*8 + L/8, swizzled col-block (L&7)^(L/8&7)
  const int lr = lane >> 3;                 // row within 8-row group
  const int lc = (lane & 7) ^ (lr & 7);     // swizzled global col-block
  const unsigned short* ag = nullptr;
  const float* agf = nullptr;
  if (CVTA)
    agf = (const float*)A_ + (size_t)zb * aBS + (size_t)(m0 + w * 8 + lr) * K + lc * 8;
  else
    ag = (const unsigned short*)A_ + (size_t)zb * aBS + (size_t)(m0 + w * 8 + lr) * K + lc * 8;
  const unsigned short* bg = Btb + (size_t)(n0 + w * 8 + lr) * K + lc * 8;
  const int sb0 = (w * 8) * 64;             // t=0 wave LDS base (shorts)
  const int sb1 = (64 + w * 8) * 64;        // t=1
  const int lofs = lane * 8;                // per-lane LDS dst for reg-staged A

  const int wm = (w & 1) * 64;              // 2 m-halves
  const int wn = (w >> 1) * 32;             // 4 n-quarters
  const int row16 = lane & 15;
  const int quad = lane >> 4;
  const int sw = row16 & 7;                 // fragment-read swizzle

  // prologue: stage tile k0=0 into buffer 0
  if (CVTA) {
    float4 av[2][2];
    #pragma unroll
    for (int t = 0; t < 2; t++) {
      av[t][0] = *(const float4*)(agf + (size_t)(t * 64) * K);
      av[t][1] = *(const float4*)(agf + (size_t)(t * 64) * K + 4);
    }
    gl_lds16(bg, Bs + sb0);
    gl_lds16(bg + (size_t)64 * K, Bs + sb1);
    *(uint4*)(As + sb0 + lofs) = pack8(av[0][0], av[0][1]);
    *(uint4*)(As + sb1 + lofs) = pack8(av[1][0], av[1][1]);
  } else {
    gl_lds16(ag, As + sb0);
    gl_lds16(ag + (size_t)64 * K, As + sb1);
    gl_lds16(bg, Bs + sb0);
    gl_lds16(bg + (size_t)64 * K, Bs + sb1);
  }
  __syncthreads();                          // drains vmcnt(0)+lgkmcnt(0) + barrier

  int bufo = 0;                             // current buffer offset (shorts)
  for (int k0 = 0; k0 < K; k0 += 64) {
    const int nbufo = bufo ^ 8192;
    const bool pf = (k0 + 64 < K);
    float4 av[2][2];
    if (pf) {                               // issue next-tile loads EARLY
      if (CVTA) {
        #pragma unroll
        for (int t = 0; t < 2; t++) {
          av[t][0] = *(const float4*)(agf + (k0 + 64) + (size_t)(t * 64) * K);
          av[t][1] = *(const float4*)(agf + (k0 + 64) + (size_t)(t * 64) * K + 4);
        }
      } else {
        gl_lds16(ag + (k0 + 64), As + nbufo + sb0);
        gl_lds16(ag + (k0 + 64) + (size_t)64 * K, As + nbufo + sb1);
      }
      gl_lds16(bg + (k0 + 64), Bs + nbufo + sb0);
      gl_lds16(bg + (k0 + 64) + (size_t)64 * K, Bs + nbufo + sb1);
    }
    short8 af[2][4], bf[2][2];
    #pragma unroll
    for (int s = 0; s < 2; s++) {
      #pragma unroll
      for (int i = 0; i < 4; i++)
        af[s][i] = *(const short8*)(As + bufo + (wm + i * 16 + row16) * 64 + ((s * 4 + quad) ^ sw) * 8);
      #pragma unroll
      for (int j = 0; j < 2; j++)
        bf[s][j] = *(const short8*)(Bs + bufo + (wn + j * 16 + row16) * 64 + ((s * 4 + quad) ^ sw) * 8);
    }
    #pragma unroll
    for (int s = 0; s < 2; s++)
      #pragma unroll
      for (int am = 0; am < 4; am++)
        #pragma unroll
        for (int bn = 0; bn < 2; bn++)
          acc[am][bn] = __builtin_amdgcn_mfma_f32_16x16x32_bf16(af[s][am], bf[s][bn], acc[am][bn], 0, 0, 0);
    if (pf && CVTA) {                       // write-late: cvt+ds_write after MFMA
      *(uint4*)(As + nbufo + sb0 + lofs) = pack8(av[0][0], av[0][1]);
      *(uint4*)(As + nbufo + sb1 + lofs) = pack8(av[1][0], av[1][1]);
    }
    __syncthreads();                        // prefetch landed; reads of bufo done
    bufo = nbufo;
  }

  // C/D layout: col = lane&15, row = (lane>>4)*4 + reg  [m89/m91-verified]
  const int col = lane & 15;
  const int r0 = quad * 4;
  #pragma unroll
  for (int am = 0; am < 4; am++) {
    #pragma unroll
    for (int bn = 0; bn < 2; bn++) {
      #pragma unroll
      for (int r = 0; r < 4; r++) {
        int m = m0 + wm + am * 16 + r0 + r;
        int n = n0 + wn + bn * 16 + col;
        float v = acc[am][bn][r];
        if (EPI == 3) v *= scale[zb * 1024 + m];
        if (EPI == 2) {
          v += bias[n];
          v = v > 0.f ? v : expm1f(v);   // ELU, alpha=1
          ((float*)outp)[(size_t)m * ldo + n] = v;
        } else {
          ((unsigned short*)outp)[(size_t)zb * oBS + (size_t)m * ldo + ocol + n] = f2b(v);
        }
      }
    }
  }
}

// ---------- launch ----------
extern "C" void kernel_launch(void* const* d_in, const int* in_sizes, int n_in,
                              void* d_out, int out_size, void* d_ws, size_t ws_size,
                              hipStream_t stream) {
  const float* x   = (const float*)d_in[0];  // (16,1024,1024)
  const int*   adj = (const int*)d_in[1];    // (16,1024,1024)
  const float* W   = (const float*)d_in[2];  // (1024,512)
  const float* a   = (const float*)d_in[3];  // (1024,1)
  const float* fcw = (const float*)d_in[4];  // (512,1024)  == Bt layout for GEMM3
  const float* fcb = (const float*)d_in[5];  // (512,)
  float* out = (float*)d_out;                // (16,1024,512) fp32
  char* ws = (char*)d_ws;

  // ws layout (~84.2 MiB)
  unsigned short* P    = (unsigned short*)(ws);               // 32MB P~ bf16
  unsigned short* hp   = (unsigned short*)(ws + 33554432);    // 32MB [agg | h] bf16 rows
  unsigned short* ht   = (unsigned short*)(ws + 67108864);    // 16MB h^T per batch
  unsigned short* Wt   = (unsigned short*)(ws + 83886080);    // 1MB
  unsigned short* fcwb = (unsigned short*)(ws + 84934656);    // 1MB
  float* f1            = (float*)(ws + 85983232);             // 64KB
  float* f2            = (float*)(ws + 86048768);             // 64KB
  float* invl          = (float*)(ws + 86114304);             // 64KB

  // 1: tiny prep (fcw cvt + W transpose)
  prep1<<<384, 256, 0, stream>>>(fcw, fcwb, W, Wt);

  // 2: GEMM1  h = x @ W  -> hp[:,512:1024]   (A = x fp32, cvt fused in staging)
  gemm_bt<1, 1><<<dim3(128, 4, 1), 512, 0, stream>>>(x, 0, Wt, 0, 1024,
                                                     hp, 0, 1024, 512, nullptr, nullptr);
  // 3: f1/f2 + h^T
  prep2<<<6144, 256, 0, stream>>>(hp, a, f1, f2, ht);
  // 4: P~ (unnormalized, bf16) + 1/rowsum   (reads adj directly)
  rowsum_P<<<4096, 256, 0, stream>>>(adj, f1, f2, invl, P);

  // 5: GEMM2 (per batch): agg = (P~ @ h) * invl  -> hp[:,0:512]
  gemm_bt<3, 0><<<dim3(8, 4, 16), 512, 0, stream>>>(P, 1024 * 1024, ht, 512 * 1024, 1024,
                                                    hp, 1024 * 1024, 1024, 0, invl, nullptr);
  // 6: GEMM3: out = elu([agg|h] @ fc_w^T + b)
  gemm_bt<2, 0><<<dim3(128, 4, 1), 512, 0, stream>>>(hp, 0, fcwb, 0, 1024,
                                                     out, 0, 512, 0, nullptr, fcb);
}